// Round 1
// baseline (1958.247 us; speedup 1.0000x reference)
//
#include <hip/hip_runtime.h>

constexpr int N_   = 16384;
constexpr int E_   = 262144;
constexpr int F_   = 16;
constexpr int H_   = 128;
constexpr int QKV_ = 512;   // HEADS*H
constexpr int DFF_ = 512;
constexpr int G_   = 128;
constexpr int L_   = 5;
constexpr float EPS_ = 1e-5f;

__device__ __forceinline__ float gelu_f(float x) {
  return 0.5f * x * (1.0f + erff(x * 0.70710678118654752440f));
}

// ---------------- embedding GEMM: [N,16] @ [16,128] + b ----------------
__global__ void k_embed(const float* __restrict__ x, const float* __restrict__ W,
                        const float* __restrict__ b, float* __restrict__ out) {
  int idx = blockIdx.x * 256 + threadIdx.x;   // N*H threads
  int n = idx >> 7, c = idx & 127;
  float s = b[c];
#pragma unroll
  for (int f = 0; f < F_; ++f) s = fmaf(x[n * F_ + f], W[f * H_ + c], s);
  out[idx] = s;
}

// ---------------- BatchNorm: deterministic 2-level stats ----------------
template<int NC>
__global__ void k_bn_stats(const float* __restrict__ xin, float* __restrict__ sums,
                           float* __restrict__ sumsq) {
  const int ROWS = N_ / 128;          // 128 rows per block, 128 blocks
  int blk = blockIdx.x;
  for (int c = threadIdx.x; c < NC; c += 256) {
    float s = 0.f, q = 0.f;
    const float* p = xin + (size_t)blk * ROWS * NC + c;
    for (int r = 0; r < ROWS; ++r) { float v = p[(size_t)r * NC]; s += v; q += v * v; }
    sums[blk * NC + c] = s;
    sumsq[blk * NC + c] = q;
  }
}

template<int NC>
__global__ void k_bn_finalize(const float* __restrict__ sums, const float* __restrict__ sumsq,
                              const float* __restrict__ g, const float* __restrict__ be,
                              float* __restrict__ a, float* __restrict__ cc) {
  int c = blockIdx.x * 128 + threadIdx.x;
  if (c >= NC) return;
  float s = 0.f, q = 0.f;
  for (int b = 0; b < 128; ++b) { s += sums[b * NC + c]; q += sumsq[b * NC + c]; }
  float mean = s * (1.0f / N_);
  float var  = q * (1.0f / N_) - mean * mean;
  float inv  = rsqrtf(var + EPS_);
  float aa   = g[c] * inv;
  a[c]  = aa;
  cc[c] = be[c] - aa * mean;
}

template<int NC>
__global__ void k_bn_apply_gelu(float* __restrict__ xio, const float* __restrict__ a,
                                const float* __restrict__ cc) {
  int idx = blockIdx.x * 256 + threadIdx.x;
  int c = idx & (NC - 1);
  float y = fmaf(a[c], xio[idx], cc[c]);
  xio[idx] = gelu_f(y);
}

// ---------------- CSR build over dst ----------------
__global__ void k_count(const int* __restrict__ dst, int* __restrict__ deg) {
  int e = blockIdx.x * 256 + threadIdx.x;
  if (e < E_) atomicAdd(&deg[dst[e]], 1);
}

__global__ void k_scan(const int* __restrict__ deg, int* __restrict__ off) {
  __shared__ int sh[256];
  int run = 0;
  for (int base = 0; base < N_; base += 256) {
    int v = deg[base + threadIdx.x];
    sh[threadIdx.x] = v;
    __syncthreads();
    for (int d = 1; d < 256; d <<= 1) {
      int add = (threadIdx.x >= d) ? sh[threadIdx.x - d] : 0;
      __syncthreads();
      sh[threadIdx.x] += add;
      __syncthreads();
    }
    off[base + threadIdx.x] = run + sh[threadIdx.x] - v;
    run += sh[255];
    __syncthreads();
  }
  if (threadIdx.x == 0) off[N_] = run;
}

__global__ void k_scatter(const int* __restrict__ dst, const int* __restrict__ off,
                          int* __restrict__ cursor, int* __restrict__ eids) {
  int e = blockIdx.x * 256 + threadIdx.x;
  if (e < E_) {
    int d = dst[e];
    int pos = off[d] + atomicAdd(&cursor[d], 1);
    eids[pos] = e;
  }
}

// ---------------- fp32 tiled GEMM: C[M,NOUT] = A[M,KDIM] @ B[KDIM,NOUT] + bias ----------------
template<int KDIM, int NOUT>
__global__ __launch_bounds__(256) void k_gemm(const float* __restrict__ A,
    const float* __restrict__ B, const float* __restrict__ bias, float* __restrict__ C) {
  __shared__ float As[32][68];   // [kk][m], padded: conflict-free b128 reads
  __shared__ float Bs[32][64];   // [kk][n]
  const int t  = threadIdx.x;
  const int tx = t & 15, ty = t >> 4;
  const int m0 = blockIdx.x * 64;
  const int n0 = blockIdx.y * 64;
  float acc[4][4] = {};
  for (int k0 = 0; k0 < KDIM; k0 += 32) {
    float4 av[2];
#pragma unroll
    for (int i = 0; i < 2; ++i) {
      int qd = t * 2 + i;            // float4 idx: m = qd>>3, kk4 = qd&7
      av[i] = *reinterpret_cast<const float4*>(&A[(size_t)(m0 + (qd >> 3)) * KDIM + k0 + (qd & 7) * 4]);
    }
#pragma unroll
    for (int i = 0; i < 2; ++i) {
      int qd = t * 2 + i; int m = qd >> 3; int kb = (qd & 7) * 4;
      As[kb + 0][m] = av[i].x; As[kb + 1][m] = av[i].y;
      As[kb + 2][m] = av[i].z; As[kb + 3][m] = av[i].w;
    }
#pragma unroll
    for (int i = 0; i < 2; ++i) {
      int qd = t * 2 + i;            // kk = qd>>4, n4 = qd&15
      float4 bv = *reinterpret_cast<const float4*>(&B[(size_t)(k0 + (qd >> 4)) * NOUT + n0 + (qd & 15) * 4]);
      *reinterpret_cast<float4*>(&Bs[qd >> 4][(qd & 15) * 4]) = bv;
    }
    __syncthreads();
#pragma unroll
    for (int kk = 0; kk < 32; ++kk) {
      float4 a4 = *reinterpret_cast<const float4*>(&As[kk][ty * 4]);
      float4 b4 = *reinterpret_cast<const float4*>(&Bs[kk][tx * 4]);
      float a[4] = {a4.x, a4.y, a4.z, a4.w};
      float b[4] = {b4.x, b4.y, b4.z, b4.w};
#pragma unroll
      for (int i = 0; i < 4; ++i)
#pragma unroll
        for (int j = 0; j < 4; ++j) acc[i][j] = fmaf(a[i], b[j], acc[i][j]);
    }
    __syncthreads();
  }
  float4 bb = *reinterpret_cast<const float4*>(&bias[n0 + tx * 4]);
  float bias4[4] = {bb.x, bb.y, bb.z, bb.w};
#pragma unroll
  for (int i = 0; i < 4; ++i) {
    int m = m0 + ty * 4 + i;
    float4 o = {acc[i][0] + bias4[0], acc[i][1] + bias4[1],
                acc[i][2] + bias4[2], acc[i][3] + bias4[3]};
    *reinterpret_cast<float4*>(&C[(size_t)m * NOUT + n0 + tx * 4]) = o;
  }
}

// ---------------- fused per-node attention (one wave per dst node) ----------------
__global__ __launch_bounds__(256) void k_attn(const float* __restrict__ q, const float* __restrict__ k,
    const float* __restrict__ v, const int* __restrict__ esrc, const int* __restrict__ eids,
    const int* __restrict__ off, float* __restrict__ outp) {
  const int wave = threadIdx.x >> 6;
  const int lane = threadIdx.x & 63;
  const int node = blockIdx.x * 4 + wave;
  const float scale = 0.08838834764831845f;   // 1/sqrt(128)
  const float4* q4 = reinterpret_cast<const float4*>(q + (size_t)node * QKV_);
  float4 qa = q4[lane * 2], qb = q4[lane * 2 + 1];
  float m = -INFINITY, den = 0.f;
  float acc[8] = {0.f, 0.f, 0.f, 0.f, 0.f, 0.f, 0.f, 0.f};
  const int s0 = off[node], s1 = off[node + 1];
  for (int t = s0; t < s1; ++t) {
    int e = eids[t];
    int s = esrc[e];
    const float4* k4 = reinterpret_cast<const float4*>(k + (size_t)s * QKV_);
    float4 ka = k4[lane * 2], kb = k4[lane * 2 + 1];
    float p = qa.x * ka.x + qa.y * ka.y + qa.z * ka.z + qa.w * ka.w
            + qb.x * kb.x + qb.y * kb.y + qb.z * kb.z + qb.w * kb.w;
    // reduce over the 16-lane group that owns this head
    p += __shfl_xor(p, 1); p += __shfl_xor(p, 2);
    p += __shfl_xor(p, 4); p += __shfl_xor(p, 8);
    float logit = p * scale;
    float nm = fmaxf(m, logit);
    float co = __expf(m - nm);       // 0 when m = -inf on first edge
    float pe = __expf(logit - nm);
    den = den * co + pe;
    const float4* v4 = reinterpret_cast<const float4*>(v + (size_t)s * QKV_);
    float4 va = v4[lane * 2], vb = v4[lane * 2 + 1];
    acc[0] = acc[0] * co + pe * va.x; acc[1] = acc[1] * co + pe * va.y;
    acc[2] = acc[2] * co + pe * va.z; acc[3] = acc[3] * co + pe * va.w;
    acc[4] = acc[4] * co + pe * vb.x; acc[5] = acc[5] * co + pe * vb.y;
    acc[6] = acc[6] * co + pe * vb.z; acc[7] = acc[7] * co + pe * vb.w;
    m = nm;
  }
  float inv = 1.f / (den + 1e-16f);
  float r[8];
#pragma unroll
  for (int j = 0; j < 8; ++j) {
    r[j] = acc[j] * inv;
    r[j] += __shfl_xor(r[j], 16);
    r[j] += __shfl_xor(r[j], 32);
    r[j] *= 0.25f;                 // mean over 4 heads
  }
  if (lane < 16) {
    float4 o0 = {r[0], r[1], r[2], r[3]};
    float4 o1 = {r[4], r[5], r[6], r[7]};
    float4* op = reinterpret_cast<float4*>(outp + (size_t)node * H_ + lane * 8);
    op[0] = o0; op[1] = o1;
  }
}

// ---------------- beta gate: out = beta*xr + (1-beta)*out ----------------
__global__ __launch_bounds__(256) void k_beta(const float* __restrict__ xr, float* __restrict__ io,
                                              const float* __restrict__ Wb) {
  const int wave = threadIdx.x >> 6;
  const int lane = threadIdx.x & 63;
  const int node = blockIdx.x * 4 + wave;
  float o0 = io[(size_t)node * H_ + lane], o1 = io[(size_t)node * H_ + lane + 64];
  float x0 = xr[(size_t)node * H_ + lane], x1 = xr[(size_t)node * H_ + lane + 64];
  float s = o0 * (Wb[lane] + Wb[256 + lane]) + x0 * (Wb[128 + lane] - Wb[256 + lane])
          + o1 * (Wb[lane + 64] + Wb[256 + lane + 64]) + x1 * (Wb[128 + lane + 64] - Wb[256 + lane + 64]);
#pragma unroll
  for (int d = 1; d < 64; d <<= 1) s += __shfl_xor(s, d);
  float beta = 1.f / (1.f + __expf(-s));
  io[(size_t)node * H_ + lane]      = beta * x0 + (1.f - beta) * o0;
  io[(size_t)node * H_ + lane + 64] = beta * x1 + (1.f - beta) * o1;
}

// ---------------- graph max-pool + prediction ----------------
__global__ void k_pool_init(unsigned int* __restrict__ pooled) {
  int i = blockIdx.x * 64 + threadIdx.x;
  if (i < G_ * H_) pooled[i] = 0x007FFFFFu;   // ordered-encoding of -inf
}

__global__ void k_pool(const float* __restrict__ h, const int* __restrict__ batch,
                       unsigned int* __restrict__ pooled) {
  int idx = blockIdx.x * 256 + threadIdx.x;   // N*H
  int n = idx >> 7, c = idx & 127;
  unsigned u = __float_as_uint(h[idx]);
  u = (u & 0x80000000u) ? ~u : (u | 0x80000000u);
  atomicMax(&pooled[batch[n] * H_ + c], u);
}

__global__ void k_pred(const unsigned int* __restrict__ pooled, const float* __restrict__ predW,
                       const float* __restrict__ predb, float* __restrict__ out) {
  int g = blockIdx.x;
  int lane = threadIdx.x;   // 64
  float s = 0.f;
  for (int c = lane; c < H_; c += 64) {
    unsigned u = pooled[g * H_ + c];
    u = (u & 0x80000000u) ? (u & 0x7FFFFFFFu) : ~u;
    s += __uint_as_float(u) * predW[c];
  }
#pragma unroll
  for (int d = 1; d < 64; d <<= 1) s += __shfl_xor(s, d);
  if (lane == 0) out[g] = s + predb[0];
}

extern "C" void kernel_launch(void* const* d_in, const int* in_sizes, int n_in,
                              void* d_out, int out_size, void* d_ws, size_t ws_size,
                              hipStream_t stream) {
  const float* x      = (const float*)d_in[0];
  const int*   edge   = (const int*)d_in[1];
  const int*   esrc   = edge;
  const int*   edst   = edge + E_;
  const int*   batch  = (const int*)d_in[2];
  const float* embW   = (const float*)d_in[3];
  const float* embb   = (const float*)d_in[4];
  const float* emb_g  = (const float*)d_in[5];
  const float* emb_be = (const float*)d_in[6];
  const float* Wq     = (const float*)d_in[7];
  const float* bq     = (const float*)d_in[8];
  const float* Wk     = (const float*)d_in[9];
  const float* bk     = (const float*)d_in[10];
  const float* Wv     = (const float*)d_in[11];
  const float* bv     = (const float*)d_in[12];
  const float* Wskip  = (const float*)d_in[13];
  const float* bskip  = (const float*)d_in[14];
  const float* Wbeta  = (const float*)d_in[15];
  const float* W1     = (const float*)d_in[16];
  const float* b1     = (const float*)d_in[17];
  const float* g1     = (const float*)d_in[18];
  const float* be1    = (const float*)d_in[19];
  const float* W2     = (const float*)d_in[20];
  const float* b2     = (const float*)d_in[21];
  const float* predW  = (const float*)d_in[22];
  const float* predb  = (const float*)d_in[23];

  // ---- workspace layout (floats) ----
  float* ws   = (float*)d_ws;
  float* h    = ws;                              // N*H
  float* hn   = h   + (size_t)N_ * H_;           // N*H
  float* q    = hn  + (size_t)N_ * H_;           // N*512
  float* kb_  = q   + (size_t)N_ * QKV_;         // N*512
  float* vb_  = kb_ + (size_t)N_ * QKV_;         // N*512
  float* xr   = vb_ + (size_t)N_ * QKV_;         // N*H
  float* attn = xr  + (size_t)N_ * H_;           // N*H
  float* t1   = q;                               // reuse q after attention
  float* stats  = attn + (size_t)N_ * H_;        // 2*128*512
  float* a_c    = stats + 2 * 128 * DFF_;        // 512
  float* c_c    = a_c + DFF_;                    // 512
  unsigned int* pooled = (unsigned int*)(c_c + DFF_);  // G*H
  int* ints   = (int*)(pooled + G_ * H_);
  int* deg    = ints;                 // N
  int* offs   = deg + N_;             // N+1
  int* cursor = offs + N_ + 1;        // N
  int* eids   = cursor + N_;          // E

  // ---- CSR build (per-call, deterministic counts) ----
  hipMemsetAsync(deg, 0, N_ * sizeof(int), stream);
  hipMemsetAsync(cursor, 0, N_ * sizeof(int), stream);
  k_count  <<<E_ / 256, 256, 0, stream>>>(edst, deg);
  k_scan   <<<1, 256, 0, stream>>>(deg, offs);
  k_scatter<<<E_ / 256, 256, 0, stream>>>(edst, offs, cursor, eids);

  // ---- embedding + BN + GELU ----
  k_embed<<<N_ * H_ / 256, 256, 0, stream>>>(x, embW, embb, h);
  k_bn_stats<128>   <<<128, 256, 0, stream>>>(h, stats, stats + 128 * 128);
  k_bn_finalize<128><<<1, 128, 0, stream>>>(stats, stats + 128 * 128, emb_g, emb_be, a_c, c_c);
  k_bn_apply_gelu<128><<<N_ * H_ / 256, 256, 0, stream>>>(h, a_c, c_c);

  dim3 g512(N_ / 64, QKV_ / 64);
  dim3 g128(N_ / 64, H_ / 64);
  for (int l = 0; l < L_; ++l) {
    const float* Wq_ = Wq + (size_t)l * H_ * QKV_;  const float* bq_ = bq + (size_t)l * QKV_;
    const float* Wk_ = Wk + (size_t)l * H_ * QKV_;  const float* bk_ = bk + (size_t)l * QKV_;
    const float* Wv_ = Wv + (size_t)l * H_ * QKV_;  const float* bv_ = bv + (size_t)l * QKV_;
    const float* Ws_ = Wskip + (size_t)l * H_ * H_; const float* bs_ = bskip + (size_t)l * H_;
    const float* Wb_ = Wbeta + (size_t)l * 3 * H_;
    const float* W1_ = W1 + (size_t)l * H_ * DFF_;  const float* b1_ = b1 + (size_t)l * DFF_;
    const float* g1_ = g1 + (size_t)l * DFF_;       const float* be1_ = be1 + (size_t)l * DFF_;
    const float* W2_ = W2 + (size_t)l * DFF_ * H_;  const float* b2_ = b2 + (size_t)l * H_;

    k_gemm<128, 512><<<g512, 256, 0, stream>>>(h, Wq_, bq_, q);
    k_gemm<128, 512><<<g512, 256, 0, stream>>>(h, Wk_, bk_, kb_);
    k_gemm<128, 512><<<g512, 256, 0, stream>>>(h, Wv_, bv_, vb_);
    k_gemm<128, 128><<<g128, 256, 0, stream>>>(h, Ws_, bs_, xr);

    k_attn<<<N_ / 4, 256, 0, stream>>>(q, kb_, vb_, esrc, eids, offs, attn);
    k_beta<<<N_ / 4, 256, 0, stream>>>(xr, attn, Wb_);

    k_gemm<128, 512><<<g512, 256, 0, stream>>>(attn, W1_, b1_, t1);
    k_bn_stats<512>   <<<128, 256, 0, stream>>>(t1, stats, stats + 128 * 512);
    k_bn_finalize<512><<<4, 128, 0, stream>>>(stats, stats + 128 * 512, g1_, be1_, a_c, c_c);
    k_bn_apply_gelu<512><<<N_ * DFF_ / 256, 256, 0, stream>>>(t1, a_c, c_c);

    k_gemm<512, 128><<<g128, 256, 0, stream>>>(t1, W2_, b2_, hn);
    float* tmp = h; h = hn; hn = tmp;
  }

  // ---- pooling + prediction ----
  k_pool_init<<<G_ * H_ / 64, 64, 0, stream>>>(pooled);
  k_pool<<<N_ * H_ / 256, 256, 0, stream>>>(h, batch, pooled);
  k_pred<<<G_, 64, 0, stream>>>(pooled, predW, predb, (float*)d_out);
}

// Round 2
// 1028.357 us; speedup vs baseline: 1.9042x; 1.9042x over previous
//
#include <hip/hip_runtime.h>
#include <hip/hip_bf16.h>

using bf16 = __hip_bfloat16;
typedef __attribute__((ext_vector_type(8))) short bf16x8;
typedef __attribute__((ext_vector_type(4))) float f32x4;

constexpr int N_   = 16384;
constexpr int E_   = 262144;
constexpr int F_   = 16;
constexpr int H_   = 128;
constexpr int QKV3_= 1536;   // q|k|v interleaved per node
constexpr int NFUSE_ = 1664; // q(512)|k(512)|v(512)|skip(128)
constexpr int DFF_ = 512;
constexpr int G_   = 128;
constexpr int L_   = 5;
constexpr float EPS_ = 1e-5f;

constexpr int WCATSZ = NFUSE_ * 128;   // 212992
constexpr int W1TSZ  = 512 * 128;      // 65536
constexpr int W2TSZ  = 512 * 128;      // 65536
constexpr int PER_L  = WCATSZ + W1TSZ + W2TSZ;

__device__ __forceinline__ float gelu_f(float x) {
  return 0.5f * x * (1.0f + erff(x * 0.70710678118654752440f));
}

__device__ __forceinline__ void unpack8(const uint4 w, float* f) {
  f[0] = __uint_as_float(w.x << 16); f[1] = __uint_as_float(w.x & 0xFFFF0000u);
  f[2] = __uint_as_float(w.y << 16); f[3] = __uint_as_float(w.y & 0xFFFF0000u);
  f[4] = __uint_as_float(w.z << 16); f[5] = __uint_as_float(w.z & 0xFFFF0000u);
  f[6] = __uint_as_float(w.w << 16); f[7] = __uint_as_float(w.w & 0xFFFF0000u);
}

// ---------------- weight transpose+cast prep (once per call) ----------------
__global__ void k_prep(const float* __restrict__ Wq, const float* __restrict__ Wk,
                       const float* __restrict__ Wv, const float* __restrict__ Ws,
                       const float* __restrict__ W1, const float* __restrict__ W2,
                       const float* __restrict__ bq, const float* __restrict__ bk,
                       const float* __restrict__ bv, const float* __restrict__ bs,
                       bf16* __restrict__ Wcat, bf16* __restrict__ W1t,
                       bf16* __restrict__ W2t, float* __restrict__ bcat) {
  int idx = blockIdx.x * 256 + threadIdx.x;
  const int total = 5 * PER_L;
  if (idx < total) {
    int l = idx / PER_L, t = idx % PER_L;
    if (t < WCATSZ) {
      int n = t >> 7, kk = t & 127;
      float v;
      if (n < 512)       v = Wq[((size_t)l * 128 + kk) * 512 + n];
      else if (n < 1024) v = Wk[((size_t)l * 128 + kk) * 512 + n - 512];
      else if (n < 1536) v = Wv[((size_t)l * 128 + kk) * 512 + n - 1024];
      else               v = Ws[((size_t)l * 128 + kk) * 128 + n - 1536];
      Wcat[(size_t)l * WCATSZ + t] = __float2bfloat16(v);
    } else if (t < WCATSZ + W1TSZ) {
      int u = t - WCATSZ; int n = u >> 7, kk = u & 127;   // W1t[n][kk], n<512
      W1t[(size_t)l * W1TSZ + u] = __float2bfloat16(W1[((size_t)l * 128 + kk) * 512 + n]);
    } else {
      int u = t - WCATSZ - W1TSZ; int n = u >> 9, kk = u & 511;  // W2t[n][kk], n<128
      W2t[(size_t)l * W2TSZ + u] = __float2bfloat16(W2[((size_t)l * 512 + kk) * 128 + n]);
    }
  } else {
    int j = idx - total;
    if (j < 5 * NFUSE_) {
      int l = j / NFUSE_, c = j % NFUSE_;
      float v = (c < 512)  ? bq[l * 512 + c]
              : (c < 1024) ? bk[l * 512 + c - 512]
              : (c < 1536) ? bv[l * 512 + c - 1024]
              :              bs[l * 128 + c - 1536];
      bcat[j] = v;
    }
  }
}

// ---------------- embedding GEMM: [N,16] @ [16,128] + b ----------------
__global__ void k_embed(const float* __restrict__ x, const float* __restrict__ W,
                        const float* __restrict__ b, float* __restrict__ out) {
  int idx = blockIdx.x * 256 + threadIdx.x;
  int n = idx >> 7, c = idx & 127;
  float s = b[c];
#pragma unroll
  for (int f = 0; f < F_; ++f) s = fmaf(x[n * F_ + f], W[f * H_ + c], s);
  out[idx] = s;
}

// ---------------- BatchNorm: deterministic 2-level stats ----------------
template<int NC>
__global__ void k_bn_stats(const float* __restrict__ xin, float* __restrict__ sums,
                           float* __restrict__ sumsq) {
  const int ROWS = N_ / 128;
  int blk = blockIdx.x;
  for (int c = threadIdx.x; c < NC; c += 256) {
    float s = 0.f, q = 0.f;
    const float* p = xin + (size_t)blk * ROWS * NC + c;
    for (int r = 0; r < ROWS; ++r) { float v = p[(size_t)r * NC]; s += v; q += v * v; }
    sums[blk * NC + c] = s;
    sumsq[blk * NC + c] = q;
  }
}

template<int NC>
__global__ void k_bn_finalize(const float* __restrict__ sums, const float* __restrict__ sumsq,
                              const float* __restrict__ g, const float* __restrict__ be,
                              float* __restrict__ a, float* __restrict__ cc) {
  int c = blockIdx.x * 128 + threadIdx.x;
  if (c >= NC) return;
  float s = 0.f, q = 0.f;
  for (int b = 0; b < 128; ++b) { s += sums[b * NC + c]; q += sumsq[b * NC + c]; }
  float mean = s * (1.0f / N_);
  float var  = q * (1.0f / N_) - mean * mean;
  float inv  = rsqrtf(var + EPS_);
  float aa   = g[c] * inv;
  a[c]  = aa;
  cc[c] = be[c] - aa * mean;
}

template<int NC>
__global__ void k_bn_apply_gelu_cast(const float* __restrict__ xin, const float* __restrict__ a,
                                     const float* __restrict__ cc, bf16* __restrict__ outb) {
  int idx = blockIdx.x * 256 + threadIdx.x;
  int c = idx & (NC - 1);
  float y = fmaf(a[c], xin[idx], cc[c]);
  outb[idx] = __float2bfloat16(gelu_f(y));
}

// ---------------- CSR build over dst ----------------
__global__ void k_count(const int* __restrict__ dst, int* __restrict__ deg) {
  int e = blockIdx.x * 256 + threadIdx.x;
  if (e < E_) atomicAdd(&deg[dst[e]], 1);
}

__global__ void k_scan(const int* __restrict__ deg, int* __restrict__ off) {
  __shared__ int sh[256];
  int run = 0;
  for (int base = 0; base < N_; base += 256) {
    int v = deg[base + threadIdx.x];
    sh[threadIdx.x] = v;
    __syncthreads();
    for (int d = 1; d < 256; d <<= 1) {
      int add = (threadIdx.x >= d) ? sh[threadIdx.x - d] : 0;
      __syncthreads();
      sh[threadIdx.x] += add;
      __syncthreads();
    }
    off[base + threadIdx.x] = run + sh[threadIdx.x] - v;
    run += sh[255];
    __syncthreads();
  }
  if (threadIdx.x == 0) off[N_] = run;
}

__global__ void k_scatter(const int* __restrict__ src, const int* __restrict__ dst,
                          const int* __restrict__ off, int* __restrict__ cursor,
                          int* __restrict__ srcs) {
  int e = blockIdx.x * 256 + threadIdx.x;
  if (e < E_) {
    int d = dst[e];
    int pos = off[d] + atomicAdd(&cursor[d], 1);
    srcs[pos] = src[e];
  }
}

// ---------------- bf16 MFMA GEMM: C[M,NOUT] = A[M,K] @ BT[NOUT,K]^T + bias ----------------
// MODE 0: fp32 out. MODE 1: fp32 + bf16 out. MODE 2: fused qkv routing (bf16 QKV / fp32 xr).
template<int KDIM, int NOUT, int TM, int MODE>
__global__ __launch_bounds__(256) void k_mfma(
    const bf16* __restrict__ A, const bf16* __restrict__ BT,
    const float* __restrict__ bias,
    float* __restrict__ outF, bf16* __restrict__ outB,
    bf16* __restrict__ QKVp, float* __restrict__ xrp) {
  constexpr int MF = TM / 32;
  __shared__ bf16 As[TM][72];
  __shared__ bf16 Bs[128][72];
  const int tid = threadIdx.x;
  const int wid = tid >> 6, lane = tid & 63;
  const int wr = wid >> 1, wc = wid & 1;
  const int m0 = blockIdx.x * TM, n0 = blockIdx.y * 128;
  const int ln = lane & 15, lq = lane >> 4;
  f32x4 acc[MF][4];
#pragma unroll
  for (int i = 0; i < MF; ++i)
#pragma unroll
    for (int j = 0; j < 4; ++j) acc[i][j] = (f32x4){0.f, 0.f, 0.f, 0.f};

  for (int k0 = 0; k0 < KDIM; k0 += 64) {
#pragma unroll
    for (int u = tid; u < TM * 8; u += 256) {
      int r = u >> 3, c = u & 7;
      *(uint4*)(&As[r][c * 8]) = *(const uint4*)(A + (size_t)(m0 + r) * KDIM + k0 + c * 8);
    }
#pragma unroll
    for (int u = tid; u < 1024; u += 256) {
      int r = u >> 3, c = u & 7;
      *(uint4*)(&Bs[r][c * 8]) = *(const uint4*)(BT + (size_t)(n0 + r) * KDIM + k0 + c * 8);
    }
    __syncthreads();
#pragma unroll
    for (int kk = 0; kk < 2; ++kk) {
      bf16x8 af[MF], bg[4];
#pragma unroll
      for (int i = 0; i < MF; ++i)
        af[i] = *(const bf16x8*)(&As[wr * (TM / 2) + i * 16 + ln][kk * 32 + lq * 8]);
#pragma unroll
      for (int j = 0; j < 4; ++j)
        bg[j] = *(const bf16x8*)(&Bs[wc * 64 + j * 16 + ln][kk * 32 + lq * 8]);
#pragma unroll
      for (int i = 0; i < MF; ++i)
#pragma unroll
        for (int j = 0; j < 4; ++j)
          acc[i][j] = __builtin_amdgcn_mfma_f32_16x16x32_bf16(af[i], bg[j], acc[i][j], 0, 0, 0);
    }
    __syncthreads();
  }
#pragma unroll
  for (int i = 0; i < MF; ++i) {
#pragma unroll
    for (int j = 0; j < 4; ++j) {
      int gcol = n0 + wc * 64 + j * 16 + ln;
      float bv = bias[gcol];
      int row0 = m0 + wr * (TM / 2) + i * 16 + lq * 4;
#pragma unroll
      for (int qq = 0; qq < 4; ++qq) {
        float val = acc[i][j][qq] + bv;
        int row = row0 + qq;
        if (MODE == 0) {
          outF[(size_t)row * NOUT + gcol] = val;
        } else if (MODE == 1) {
          outF[(size_t)row * NOUT + gcol] = val;
          outB[(size_t)row * NOUT + gcol] = __float2bfloat16(val);
        } else {
          if (n0 < 1536) QKVp[(size_t)row * QKV3_ + gcol] = __float2bfloat16(val);
          else           xrp[(size_t)row * H_ + (gcol - 1536)] = val;
        }
      }
    }
  }
}

// ---------------- fused attention + beta gate (one wave per dst node) ----------------
__global__ __launch_bounds__(256) void k_attn(const bf16* __restrict__ QKV,
    const float* __restrict__ xr, const float* __restrict__ Wb,
    const int* __restrict__ srcs, const int* __restrict__ off,
    bf16* __restrict__ gated) {
  const int wave = threadIdx.x >> 6;
  const int lane = threadIdx.x & 63;
  const int node = blockIdx.x * 4 + wave;
  const float scale = 0.08838834764831845f;   // 1/sqrt(128)
  const uint4* qp = reinterpret_cast<const uint4*>(QKV + (size_t)node * QKV3_);
  uint4 qw = qp[lane];
  float qf[8]; unpack8(qw, qf);
  float m = -INFINITY, den = 0.f;
  float acc[8] = {0.f, 0.f, 0.f, 0.f, 0.f, 0.f, 0.f, 0.f};
  const int s0 = off[node], s1 = off[node + 1];
  if (s0 < s1) {
    int scur = srcs[s0];
    const uint4* kp = reinterpret_cast<const uint4*>(QKV + (size_t)scur * QKV3_ + 512);
    uint4 kw = kp[lane];
    uint4 vw = kp[64 + lane];
    for (int t = s0; t < s1; ++t) {
      int snext = (t + 1 < s1) ? srcs[t + 1] : scur;
      const uint4* knp = reinterpret_cast<const uint4*>(QKV + (size_t)snext * QKV3_ + 512);
      uint4 kn = knp[lane];
      uint4 vn = knp[64 + lane];
      float kf[8]; unpack8(kw, kf);
      float p = qf[0] * kf[0] + qf[1] * kf[1] + qf[2] * kf[2] + qf[3] * kf[3]
              + qf[4] * kf[4] + qf[5] * kf[5] + qf[6] * kf[6] + qf[7] * kf[7];
      p += __shfl_xor(p, 1); p += __shfl_xor(p, 2);
      p += __shfl_xor(p, 4); p += __shfl_xor(p, 8);
      float logit = p * scale;
      float nm = fmaxf(m, logit);
      float co = __expf(m - nm);
      float pe = __expf(logit - nm);
      den = den * co + pe;
      float vf[8]; unpack8(vw, vf);
#pragma unroll
      for (int j = 0; j < 8; ++j) acc[j] = acc[j] * co + pe * vf[j];
      m = nm;
      kw = kn; vw = vn;
    }
  }
  float inv = 1.f / (den + 1e-16f);
  float r[8];
#pragma unroll
  for (int j = 0; j < 8; ++j) {
    r[j] = acc[j] * inv;
    r[j] += __shfl_xor(r[j], 16);
    r[j] += __shfl_xor(r[j], 32);
    r[j] *= 0.25f;                 // mean over 4 heads; all lanes hold result
  }
  // fused beta gate
  const int c0 = (lane & 15) * 8;
  float xv[8];
  const float* xp = xr + (size_t)node * H_ + c0;
#pragma unroll
  for (int j = 0; j < 8; ++j) xv[j] = xp[j];
  float s = 0.f;
#pragma unroll
  for (int j = 0; j < 8; ++j) {
    int c = c0 + j;
    s += r[j] * (Wb[c] + Wb[256 + c]) + xv[j] * (Wb[128 + c] - Wb[256 + c]);
  }
  s += __shfl_xor(s, 1); s += __shfl_xor(s, 2);
  s += __shfl_xor(s, 4); s += __shfl_xor(s, 8);
  float beta = 1.f / (1.f + __expf(-s));
  if (lane < 16) {
    union { uint4 u4; bf16 h[8]; } pk;
#pragma unroll
    for (int j = 0; j < 8; ++j) pk.h[j] = __float2bfloat16(beta * xv[j] + (1.f - beta) * r[j]);
    *reinterpret_cast<uint4*>(gated + (size_t)node * H_ + c0) = pk.u4;
  }
}

// ---------------- graph max-pool + prediction ----------------
__global__ void k_pool_init(unsigned int* __restrict__ pooled) {
  int i = blockIdx.x * 64 + threadIdx.x;
  if (i < G_ * H_) pooled[i] = 0x007FFFFFu;
}

__global__ void k_pool(const float* __restrict__ h, const int* __restrict__ batch,
                       unsigned int* __restrict__ pooled) {
  int idx = blockIdx.x * 256 + threadIdx.x;
  int n = idx >> 7, c = idx & 127;
  unsigned u = __float_as_uint(h[idx]);
  u = (u & 0x80000000u) ? ~u : (u | 0x80000000u);
  atomicMax(&pooled[batch[n] * H_ + c], u);
}

__global__ void k_pred(const unsigned int* __restrict__ pooled, const float* __restrict__ predW,
                       const float* __restrict__ predb, float* __restrict__ out) {
  int g = blockIdx.x;
  int lane = threadIdx.x;
  float s = 0.f;
  for (int c = lane; c < H_; c += 64) {
    unsigned u = pooled[g * H_ + c];
    u = (u & 0x80000000u) ? (u & 0x7FFFFFFFu) : ~u;
    s += __uint_as_float(u) * predW[c];
  }
#pragma unroll
  for (int d = 1; d < 64; d <<= 1) s += __shfl_xor(s, d);
  if (lane == 0) out[g] = s + predb[0];
}

extern "C" void kernel_launch(void* const* d_in, const int* in_sizes, int n_in,
                              void* d_out, int out_size, void* d_ws, size_t ws_size,
                              hipStream_t stream) {
  const float* x      = (const float*)d_in[0];
  const int*   edge   = (const int*)d_in[1];
  const int*   esrc   = edge;
  const int*   edst   = edge + E_;
  const int*   batch  = (const int*)d_in[2];
  const float* embW   = (const float*)d_in[3];
  const float* embb   = (const float*)d_in[4];
  const float* emb_g  = (const float*)d_in[5];
  const float* emb_be = (const float*)d_in[6];
  const float* Wq     = (const float*)d_in[7];
  const float* bq     = (const float*)d_in[8];
  const float* Wk     = (const float*)d_in[9];
  const float* bk     = (const float*)d_in[10];
  const float* Wv     = (const float*)d_in[11];
  const float* bv     = (const float*)d_in[12];
  const float* Wskip  = (const float*)d_in[13];
  const float* bskip  = (const float*)d_in[14];
  const float* Wbeta  = (const float*)d_in[15];
  const float* W1     = (const float*)d_in[16];
  const float* b1     = (const float*)d_in[17];
  const float* g1     = (const float*)d_in[18];
  const float* be1    = (const float*)d_in[19];
  const float* W2     = (const float*)d_in[20];
  const float* b2     = (const float*)d_in[21];
  const float* predW  = (const float*)d_in[22];
  const float* predb  = (const float*)d_in[23];

  // ---- workspace layout ----
  float* ws = (float*)d_ws;
  size_t o = 0;
  auto alloc_f = [&](size_t n) { float* p = ws + o; o += n; return p; };
  float* h32   = alloc_f((size_t)N_ * H_);       // final-layer fp32 activations
  float* t1    = alloc_f((size_t)N_ * DFF_);     // FFN mid fp32 (also embed pre-BN)
  float* xr    = alloc_f((size_t)N_ * H_);
  float* stats = alloc_f(2 * 128 * DFF_);
  float* a_c   = alloc_f(DFF_);
  float* c_c   = alloc_f(DFF_);
  float* bcat  = alloc_f(5 * NFUSE_);
  bf16* bp = (bf16*)(ws + o);
  size_t ob = 0;
  auto alloc_b = [&](size_t n) { bf16* p = bp + ob; ob += n; return p; };
  bf16* QKV  = alloc_b((size_t)N_ * QKV3_);
  bf16* hb   = alloc_b((size_t)N_ * H_);
  bf16* gated= alloc_b((size_t)N_ * H_);
  bf16* t1b  = alloc_b((size_t)N_ * DFF_);
  bf16* Wcat = alloc_b((size_t)5 * WCATSZ);
  bf16* W1t  = alloc_b((size_t)5 * W1TSZ);
  bf16* W2t  = alloc_b((size_t)5 * W2TSZ);
  unsigned int* pooled = (unsigned int*)(bp + ob);
  int* deg    = (int*)(pooled + G_ * H_);
  int* offs   = deg + N_;
  int* cursor = offs + N_ + 1;
  int* srcs   = cursor + N_;

  // ---- weight prep ----
  int prep_total = 5 * PER_L + 5 * NFUSE_;
  k_prep<<<(prep_total + 255) / 256, 256, 0, stream>>>(Wq, Wk, Wv, Wskip, W1, W2,
                                                       bq, bk, bv, bskip, Wcat, W1t, W2t, bcat);

  // ---- CSR build ----
  hipMemsetAsync(deg, 0, N_ * sizeof(int), stream);
  hipMemsetAsync(cursor, 0, N_ * sizeof(int), stream);
  k_count  <<<E_ / 256, 256, 0, stream>>>(edst, deg);
  k_scan   <<<1, 256, 0, stream>>>(deg, offs);
  k_scatter<<<E_ / 256, 256, 0, stream>>>(esrc, edst, offs, cursor, srcs);

  // ---- embedding + BN + GELU -> bf16 ----
  k_embed<<<N_ * H_ / 256, 256, 0, stream>>>(x, embW, embb, t1);
  k_bn_stats<128>   <<<128, 256, 0, stream>>>(t1, stats, stats + 128 * 128);
  k_bn_finalize<128><<<1, 128, 0, stream>>>(stats, stats + 128 * 128, emb_g, emb_be, a_c, c_c);
  k_bn_apply_gelu_cast<128><<<N_ * H_ / 256, 256, 0, stream>>>(t1, a_c, c_c, hb);

  for (int l = 0; l < L_; ++l) {
    const float* Wb_ = Wbeta + (size_t)l * 3 * H_;
    const float* b1_ = b1 + (size_t)l * DFF_;
    const float* g1_ = g1 + (size_t)l * DFF_;
    const float* be1_= be1 + (size_t)l * DFF_;
    const float* b2_ = b2 + (size_t)l * H_;

    k_mfma<128, NFUSE_, 128, 2><<<dim3(N_ / 128, NFUSE_ / 128), 256, 0, stream>>>(
        hb, Wcat + (size_t)l * WCATSZ, bcat + (size_t)l * NFUSE_,
        nullptr, nullptr, QKV, xr);

    k_attn<<<N_ / 4, 256, 0, stream>>>(QKV, xr, Wb_, srcs, offs, gated);

    k_mfma<128, 512, 128, 0><<<dim3(N_ / 128, 4), 256, 0, stream>>>(
        gated, W1t + (size_t)l * W1TSZ, b1_, t1, nullptr, nullptr, nullptr);

    k_bn_stats<512>   <<<128, 256, 0, stream>>>(t1, stats, stats + 128 * 512);
    k_bn_finalize<512><<<4, 128, 0, stream>>>(stats, stats + 128 * 512, g1_, be1_, a_c, c_c);
    k_bn_apply_gelu_cast<512><<<N_ * DFF_ / 256, 256, 0, stream>>>(t1, a_c, c_c, t1b);

    k_mfma<512, 128, 64, 1><<<dim3(N_ / 64, 1), 256, 0, stream>>>(
        t1b, W2t + (size_t)l * W2TSZ, b2_, h32, hb, nullptr, nullptr);
  }

  // ---- pooling + prediction ----
  k_pool_init<<<G_ * H_ / 64, 64, 0, stream>>>(pooled);
  k_pool<<<N_ * H_ / 256, 256, 0, stream>>>(h32, batch, pooled);
  k_pred<<<G_, 64, 0, stream>>>(pooled, predW, predb, (float*)d_out);
}

// Round 3
// 917.915 us; speedup vs baseline: 2.1334x; 1.1203x over previous
//
#include <hip/hip_runtime.h>
#include <hip/hip_bf16.h>

using bf16 = __hip_bfloat16;
typedef __attribute__((ext_vector_type(8))) short bf16x8;
typedef __attribute__((ext_vector_type(4))) float f32x4;

constexpr int N_   = 16384;
constexpr int E_   = 262144;
constexpr int F_   = 16;
constexpr int H_   = 128;
constexpr int QKV3_= 1536;   // q|k|v interleaved per node
constexpr int NFUSE_ = 1664; // q(512)|k(512)|v(512)|skip(128)
constexpr int DFF_ = 512;
constexpr int G_   = 128;
constexpr int L_   = 5;
constexpr float EPS_ = 1e-5f;

constexpr int WCATSZ = NFUSE_ * 128;   // 212992
constexpr int W1TSZ  = 512 * 128;      // 65536
constexpr int W2TSZ  = 512 * 128;      // 65536
constexpr int PER_L  = WCATSZ + W1TSZ + W2TSZ;

__device__ __forceinline__ float gelu_f(float x) {
  return 0.5f * x * (1.0f + erff(x * 0.70710678118654752440f));
}

__device__ __forceinline__ void unpack8(const uint4 w, float* f) {
  f[0] = __uint_as_float(w.x << 16); f[1] = __uint_as_float(w.x & 0xFFFF0000u);
  f[2] = __uint_as_float(w.y << 16); f[3] = __uint_as_float(w.y & 0xFFFF0000u);
  f[4] = __uint_as_float(w.z << 16); f[5] = __uint_as_float(w.z & 0xFFFF0000u);
  f[6] = __uint_as_float(w.w << 16); f[7] = __uint_as_float(w.w & 0xFFFF0000u);
}

// ---------------- weight transpose+cast prep (once per call) ----------------
__global__ void k_prep(const float* __restrict__ Wq, const float* __restrict__ Wk,
                       const float* __restrict__ Wv, const float* __restrict__ Ws,
                       const float* __restrict__ W1, const float* __restrict__ W2,
                       const float* __restrict__ bq, const float* __restrict__ bk,
                       const float* __restrict__ bv, const float* __restrict__ bs,
                       bf16* __restrict__ Wcat, bf16* __restrict__ W1t,
                       bf16* __restrict__ W2t, float* __restrict__ bcat) {
  int idx = blockIdx.x * 256 + threadIdx.x;
  const int total = 5 * PER_L;
  if (idx < total) {
    int l = idx / PER_L, t = idx % PER_L;
    if (t < WCATSZ) {
      int n = t >> 7, kk = t & 127;
      float v;
      if (n < 512)       v = Wq[((size_t)l * 128 + kk) * 512 + n];
      else if (n < 1024) v = Wk[((size_t)l * 128 + kk) * 512 + n - 512];
      else if (n < 1536) v = Wv[((size_t)l * 128 + kk) * 512 + n - 1024];
      else               v = Ws[((size_t)l * 128 + kk) * 128 + n - 1536];
      Wcat[(size_t)l * WCATSZ + t] = __float2bfloat16(v);
    } else if (t < WCATSZ + W1TSZ) {
      int u = t - WCATSZ; int n = u >> 7, kk = u & 127;   // W1t[n][kk], n<512
      W1t[(size_t)l * W1TSZ + u] = __float2bfloat16(W1[((size_t)l * 128 + kk) * 512 + n]);
    } else {
      int u = t - WCATSZ - W1TSZ; int n = u >> 9, kk = u & 511;  // W2t[n][kk], n<128
      W2t[(size_t)l * W2TSZ + u] = __float2bfloat16(W2[((size_t)l * 512 + kk) * 128 + n]);
    }
  } else {
    int j = idx - total;
    if (j < 5 * NFUSE_) {
      int l = j / NFUSE_, c = j % NFUSE_;
      float v = (c < 512)  ? bq[l * 512 + c]
              : (c < 1024) ? bk[l * 512 + c - 512]
              : (c < 1536) ? bv[l * 512 + c - 1024]
              :              bs[l * 128 + c - 1536];
      bcat[j] = v;
    }
  }
}

// ---------------- embedding GEMM + fused BN partial stats ----------------
__global__ __launch_bounds__(256) void k_embed2(const float* __restrict__ x,
    const float* __restrict__ W, const float* __restrict__ b,
    float* __restrict__ out, float* __restrict__ ss, float* __restrict__ sq) {
  __shared__ float xs[128][16];
  __shared__ float wsm[16][128];
  __shared__ float sr[2][128], qr[2][128];
  const int blk = blockIdx.x;          // 128 blocks x 128 rows
  const int t = threadIdx.x;
  for (int i = t; i < 16 * 128; i += 256) wsm[i >> 7][i & 127] = W[i];
  for (int i = t; i < 128 * 16; i += 256) xs[i >> 4][i & 15] = x[(size_t)blk * 2048 + i];
  __syncthreads();
  const int c = t & 127, rg = t >> 7;
  float bc = b[c];
  float s = 0.f, q = 0.f;
  for (int r = rg * 64; r < rg * 64 + 64; ++r) {
    float v = bc;
#pragma unroll
    for (int f = 0; f < 16; ++f) v = fmaf(xs[r][f], wsm[f][c], v);
    out[(size_t)(blk * 128 + r) * 128 + c] = v;
    s += v; q += v * v;
  }
  sr[rg][c] = s; qr[rg][c] = q;
  __syncthreads();
  if (t < 128) { ss[blk * 128 + t] = sr[0][t] + sr[1][t]; sq[blk * 128 + t] = qr[0][t] + qr[1][t]; }
}

// ---------------- BatchNorm finalize / apply ----------------
template<int NC>
__global__ void k_bn_finalize(const float* __restrict__ sums, const float* __restrict__ sumsq,
                              const float* __restrict__ g, const float* __restrict__ be,
                              float* __restrict__ a, float* __restrict__ cc) {
  int c = blockIdx.x * 128 + threadIdx.x;
  if (c >= NC) return;
  float s = 0.f, q = 0.f;
  for (int b = 0; b < 128; ++b) { s += sums[b * NC + c]; q += sumsq[b * NC + c]; }
  float mean = s * (1.0f / N_);
  float var  = q * (1.0f / N_) - mean * mean;
  float inv  = rsqrtf(var + EPS_);
  float aa   = g[c] * inv;
  a[c]  = aa;
  cc[c] = be[c] - aa * mean;
}

template<int NC>
__global__ void k_bn_apply_gelu_cast(const float* __restrict__ xin, const float* __restrict__ a,
                                     const float* __restrict__ cc, bf16* __restrict__ outb) {
  int idx = blockIdx.x * 256 + threadIdx.x;
  int c = idx & (NC - 1);
  float y = fmaf(a[c], xin[idx], cc[c]);
  outb[idx] = __float2bfloat16(gelu_f(y));
}

// ---------------- CSR build over dst ----------------
__global__ void k_count(const int* __restrict__ dst, int* __restrict__ deg) {
  int e = blockIdx.x * 256 + threadIdx.x;
  if (e < E_) atomicAdd(&deg[dst[e]], 1);
}

__global__ void k_bsum(const int* __restrict__ deg, int* __restrict__ bsum) {
  __shared__ int sh[256];
  int t = threadIdx.x;
  sh[t] = deg[blockIdx.x * 256 + t];
  __syncthreads();
  for (int d = 128; d > 0; d >>= 1) { if (t < d) sh[t] += sh[t + d]; __syncthreads(); }
  if (t == 0) bsum[blockIdx.x] = sh[0];
}

__global__ void k_btop(const int* __restrict__ bsum, int* __restrict__ btop) {
  int t = threadIdx.x;          // 64 threads, one wave
  int v = bsum[t];
  int s = v;
  for (int d = 1; d < 64; d <<= 1) { int o = __shfl_up(s, d); if (t >= d) s += o; }
  btop[t] = s - v;              // exclusive
}

__global__ void k_boffs(const int* __restrict__ deg, const int* __restrict__ btop,
                        int* __restrict__ offs) {
  __shared__ int sh[256];
  int t = threadIdx.x;
  int v = deg[blockIdx.x * 256 + t];
  sh[t] = v;
  __syncthreads();
  for (int d = 1; d < 256; d <<= 1) {
    int add = (t >= d) ? sh[t - d] : 0;
    __syncthreads();
    sh[t] += add;
    __syncthreads();
  }
  offs[blockIdx.x * 256 + t] = btop[blockIdx.x] + sh[t] - v;
  if (blockIdx.x == 63 && t == 255) offs[N_] = E_;
}

__global__ void k_scatter(const int* __restrict__ src, const int* __restrict__ dst,
                          const int* __restrict__ off, int* __restrict__ cursor,
                          int* __restrict__ srcs) {
  int e = blockIdx.x * 256 + threadIdx.x;
  if (e < E_) {
    int d = dst[e];
    int pos = off[d] + atomicAdd(&cursor[d], 1);
    srcs[pos] = src[e];
  }
}

// ---------------- bf16 MFMA GEMM: C[M,NOUT] = A[M,K] @ BT[NOUT,K]^T + bias ----------------
// MODE 0: fp32 out. MODE 1: fp32 + bf16 out. MODE 2: fused qkv routing.
// MODE 3: fp32 out + per-m-tile BN column partial stats.
template<int KDIM, int NOUT, int TM, int MODE>
__global__ __launch_bounds__(256) void k_mfma(
    const bf16* __restrict__ A, const bf16* __restrict__ BT,
    const float* __restrict__ bias,
    float* __restrict__ outF, bf16* __restrict__ outB,
    bf16* __restrict__ QKVp, float* __restrict__ xrp,
    float* __restrict__ ss, float* __restrict__ sq) {
  constexpr int MF = TM / 32;
  __shared__ bf16 As[TM][72];
  __shared__ bf16 Bs[128][72];
  __shared__ float sred[2][128], qred[2][128];
  const int tid = threadIdx.x;
  const int wid = tid >> 6, lane = tid & 63;
  const int wr = wid >> 1, wc = wid & 1;
  const int m0 = blockIdx.x * TM, n0 = blockIdx.y * 128;
  const int ln = lane & 15, lq = lane >> 4;
  f32x4 acc[MF][4];
#pragma unroll
  for (int i = 0; i < MF; ++i)
#pragma unroll
    for (int j = 0; j < 4; ++j) acc[i][j] = (f32x4){0.f, 0.f, 0.f, 0.f};

  for (int k0 = 0; k0 < KDIM; k0 += 64) {
#pragma unroll
    for (int u = tid; u < TM * 8; u += 256) {
      int r = u >> 3, c = u & 7;
      *(uint4*)(&As[r][c * 8]) = *(const uint4*)(A + (size_t)(m0 + r) * KDIM + k0 + c * 8);
    }
#pragma unroll
    for (int u = tid; u < 1024; u += 256) {
      int r = u >> 3, c = u & 7;
      *(uint4*)(&Bs[r][c * 8]) = *(const uint4*)(BT + (size_t)(n0 + r) * KDIM + k0 + c * 8);
    }
    __syncthreads();
#pragma unroll
    for (int kk = 0; kk < 2; ++kk) {
      bf16x8 af[MF], bg[4];
#pragma unroll
      for (int i = 0; i < MF; ++i)
        af[i] = *(const bf16x8*)(&As[wr * (TM / 2) + i * 16 + ln][kk * 32 + lq * 8]);
#pragma unroll
      for (int j = 0; j < 4; ++j)
        bg[j] = *(const bf16x8*)(&Bs[wc * 64 + j * 16 + ln][kk * 32 + lq * 8]);
#pragma unroll
      for (int i = 0; i < MF; ++i)
#pragma unroll
        for (int j = 0; j < 4; ++j)
          acc[i][j] = __builtin_amdgcn_mfma_f32_16x16x32_bf16(af[i], bg[j], acc[i][j], 0, 0, 0);
    }
    __syncthreads();
  }
  float ssj[4] = {0.f, 0.f, 0.f, 0.f}, sqj[4] = {0.f, 0.f, 0.f, 0.f};
#pragma unroll
  for (int i = 0; i < MF; ++i) {
#pragma unroll
    for (int j = 0; j < 4; ++j) {
      int gcol = n0 + wc * 64 + j * 16 + ln;
      float bv = bias[gcol];
      int row0 = m0 + wr * (TM / 2) + i * 16 + lq * 4;
#pragma unroll
      for (int qq = 0; qq < 4; ++qq) {
        float val = acc[i][j][qq] + bv;
        int row = row0 + qq;
        if (MODE == 0 || MODE == 3) {
          outF[(size_t)row * NOUT + gcol] = val;
          if (MODE == 3) { ssj[j] += val; sqj[j] += val * val; }
        } else if (MODE == 1) {
          outF[(size_t)row * NOUT + gcol] = val;
          outB[(size_t)row * NOUT + gcol] = __float2bfloat16(val);
        } else {
          if (n0 < 1536) QKVp[(size_t)row * QKV3_ + gcol] = __float2bfloat16(val);
          else           xrp[(size_t)row * H_ + (gcol - 1536)] = val;
        }
      }
    }
  }
  if constexpr (MODE == 3) {
#pragma unroll
    for (int j = 0; j < 4; ++j) {
      ssj[j] += __shfl_xor(ssj[j], 16); ssj[j] += __shfl_xor(ssj[j], 32);
      sqj[j] += __shfl_xor(sqj[j], 16); sqj[j] += __shfl_xor(sqj[j], 32);
    }
    if (lq == 0) {
#pragma unroll
      for (int j = 0; j < 4; ++j) {
        sred[wr][wc * 64 + j * 16 + ln] = ssj[j];
        qred[wr][wc * 64 + j * 16 + ln] = sqj[j];
      }
    }
    __syncthreads();
    if (tid < 128) {
      ss[(size_t)blockIdx.x * NOUT + n0 + tid] = sred[0][tid] + sred[1][tid];
      sq[(size_t)blockIdx.x * NOUT + n0 + tid] = qred[0][tid] + qred[1][tid];
    }
  }
}

// ---------------- fused attention + beta gate (one wave per dst node) ----------------
__global__ __launch_bounds__(256) void k_attn(const bf16* __restrict__ QKV,
    const float* __restrict__ xr, const float* __restrict__ Wb,
    const int* __restrict__ srcs, const int* __restrict__ off,
    bf16* __restrict__ gated) {
  const int wave = threadIdx.x >> 6;
  const int lane = threadIdx.x & 63;
  const int node = blockIdx.x * 4 + wave;
  const float scale = 0.08838834764831845f;   // 1/sqrt(128)
  const uint4* qp = reinterpret_cast<const uint4*>(QKV + (size_t)node * QKV3_);
  uint4 qw = qp[lane];
  float qf[8]; unpack8(qw, qf);
  float m = -1e30f, den = 0.f;
  float acc[8] = {0.f, 0.f, 0.f, 0.f, 0.f, 0.f, 0.f, 0.f};
  const int s0 = off[node], s1 = off[node + 1];
  if (s0 < s1) {
    int i0 = srcs[s0];
    int i1 = (s0 + 1 < s1) ? srcs[s0 + 1] : i0;
    const uint4* p0 = reinterpret_cast<const uint4*>(QKV + (size_t)i0 * QKV3_ + 512) + lane;
    const uint4* p1 = reinterpret_cast<const uint4*>(QKV + (size_t)i1 * QKV3_ + 512) + lane;
    uint4 k0 = p0[0], v0 = p0[64];
    uint4 k1 = p1[0], v1 = p1[64];
    for (int t = s0; t < s1; t += 2) {
      // prefetch edges t+2, t+3 (clamped addresses -> L2 hits on tail)
      int j0 = (t + 2 < s1) ? srcs[t + 2] : i0;
      int j1 = (t + 3 < s1) ? srcs[t + 3] : i0;
      const uint4* q0 = reinterpret_cast<const uint4*>(QKV + (size_t)j0 * QKV3_ + 512) + lane;
      const uint4* q1 = reinterpret_cast<const uint4*>(QKV + (size_t)j1 * QKV3_ + 512) + lane;
      uint4 nk0 = q0[0], nv0 = q0[64];
      uint4 nk1 = q1[0], nv1 = q1[64];
      {
        float kf[8]; unpack8(k0, kf);
        float p = qf[0] * kf[0] + qf[1] * kf[1] + qf[2] * kf[2] + qf[3] * kf[3]
                + qf[4] * kf[4] + qf[5] * kf[5] + qf[6] * kf[6] + qf[7] * kf[7];
        p += __shfl_xor(p, 1); p += __shfl_xor(p, 2);
        p += __shfl_xor(p, 4); p += __shfl_xor(p, 8);
        float logit = p * scale;
        if (logit > m + 8.f) {        // defer-max: rescale only on big jumps
          float co = __expf(m - logit);
          den *= co;
#pragma unroll
          for (int j = 0; j < 8; ++j) acc[j] *= co;
          m = logit;
        }
        float pe = __expf(logit - m);
        den += pe;
        float vf[8]; unpack8(v0, vf);
#pragma unroll
        for (int j = 0; j < 8; ++j) acc[j] = fmaf(pe, vf[j], acc[j]);
      }
      if (t + 1 < s1) {
        float kf[8]; unpack8(k1, kf);
        float p = qf[0] * kf[0] + qf[1] * kf[1] + qf[2] * kf[2] + qf[3] * kf[3]
                + qf[4] * kf[4] + qf[5] * kf[5] + qf[6] * kf[6] + qf[7] * kf[7];
        p += __shfl_xor(p, 1); p += __shfl_xor(p, 2);
        p += __shfl_xor(p, 4); p += __shfl_xor(p, 8);
        float logit = p * scale;
        if (logit > m + 8.f) {
          float co = __expf(m - logit);
          den *= co;
#pragma unroll
          for (int j = 0; j < 8; ++j) acc[j] *= co;
          m = logit;
        }
        float pe = __expf(logit - m);
        den += pe;
        float vf[8]; unpack8(v1, vf);
#pragma unroll
        for (int j = 0; j < 8; ++j) acc[j] = fmaf(pe, vf[j], acc[j]);
      }
      k0 = nk0; v0 = nv0; k1 = nk1; v1 = nv1;
    }
  }
  float inv = 1.f / (den + 1e-16f);
  float r[8];
#pragma unroll
  for (int j = 0; j < 8; ++j) {
    r[j] = acc[j] * inv;
    r[j] += __shfl_xor(r[j], 16);
    r[j] += __shfl_xor(r[j], 32);
    r[j] *= 0.25f;                 // mean over 4 heads; all lanes hold result
  }
  // fused beta gate
  const int c0 = (lane & 15) * 8;
  float xv[8];
  const float* xp = xr + (size_t)node * H_ + c0;
#pragma unroll
  for (int j = 0; j < 8; ++j) xv[j] = xp[j];
  float s = 0.f;
#pragma unroll
  for (int j = 0; j < 8; ++j) {
    int c = c0 + j;
    s += r[j] * (Wb[c] + Wb[256 + c]) + xv[j] * (Wb[128 + c] - Wb[256 + c]);
  }
  s += __shfl_xor(s, 1); s += __shfl_xor(s, 2);
  s += __shfl_xor(s, 4); s += __shfl_xor(s, 8);
  float beta = 1.f / (1.f + __expf(-s));
  if (lane < 16) {
    union { uint4 u4; bf16 h[8]; } pk;
#pragma unroll
    for (int j = 0; j < 8; ++j) pk.h[j] = __float2bfloat16(beta * xv[j] + (1.f - beta) * r[j]);
    *reinterpret_cast<uint4*>(gated + (size_t)node * H_ + c0) = pk.u4;
  }
}

// ---------------- graph max-pool + prediction ----------------
__global__ void k_pool_init(unsigned int* __restrict__ pooled) {
  int i = blockIdx.x * 64 + threadIdx.x;
  if (i < G_ * H_) pooled[i] = 0x007FFFFFu;
}

__global__ void k_pool(const float* __restrict__ h, const int* __restrict__ batch,
                       unsigned int* __restrict__ pooled) {
  int idx = blockIdx.x * 256 + threadIdx.x;
  int n = idx >> 7, c = idx & 127;
  unsigned u = __float_as_uint(h[idx]);
  u = (u & 0x80000000u) ? ~u : (u | 0x80000000u);
  atomicMax(&pooled[batch[n] * H_ + c], u);
}

__global__ void k_pred(const unsigned int* __restrict__ pooled, const float* __restrict__ predW,
                       const float* __restrict__ predb, float* __restrict__ out) {
  int g = blockIdx.x;
  int lane = threadIdx.x;
  float s = 0.f;
  for (int c = lane; c < H_; c += 64) {
    unsigned u = pooled[g * H_ + c];
    u = (u & 0x80000000u) ? (u & 0x7FFFFFFFu) : ~u;
    s += __uint_as_float(u) * predW[c];
  }
#pragma unroll
  for (int d = 1; d < 64; d <<= 1) s += __shfl_xor(s, d);
  if (lane == 0) out[g] = s + predb[0];
}

extern "C" void kernel_launch(void* const* d_in, const int* in_sizes, int n_in,
                              void* d_out, int out_size, void* d_ws, size_t ws_size,
                              hipStream_t stream) {
  const float* x      = (const float*)d_in[0];
  const int*   edge   = (const int*)d_in[1];
  const int*   esrc   = edge;
  const int*   edst   = edge + E_;
  const int*   batch  = (const int*)d_in[2];
  const float* embW   = (const float*)d_in[3];
  const float* embb   = (const float*)d_in[4];
  const float* emb_g  = (const float*)d_in[5];
  const float* emb_be = (const float*)d_in[6];
  const float* Wq     = (const float*)d_in[7];
  const float* bq     = (const float*)d_in[8];
  const float* Wk     = (const float*)d_in[9];
  const float* bk     = (const float*)d_in[10];
  const float* Wv     = (const float*)d_in[11];
  const float* bv     = (const float*)d_in[12];
  const float* Wskip  = (const float*)d_in[13];
  const float* bskip  = (const float*)d_in[14];
  const float* Wbeta  = (const float*)d_in[15];
  const float* W1     = (const float*)d_in[16];
  const float* b1     = (const float*)d_in[17];
  const float* g1     = (const float*)d_in[18];
  const float* be1    = (const float*)d_in[19];
  const float* W2     = (const float*)d_in[20];
  const float* b2     = (const float*)d_in[21];
  const float* predW  = (const float*)d_in[22];
  const float* predb  = (const float*)d_in[23];

  // ---- workspace layout ----
  float* ws = (float*)d_ws;
  size_t o = 0;
  auto alloc_f = [&](size_t n) { float* p = ws + o; o += n; return p; };
  float* h32   = alloc_f((size_t)N_ * H_);
  float* t1    = alloc_f((size_t)N_ * DFF_);
  float* xr    = alloc_f((size_t)N_ * H_);
  float* stats = alloc_f(2 * 128 * DFF_);
  float* a_c   = alloc_f(DFF_);
  float* c_c   = alloc_f(DFF_);
  float* bcat  = alloc_f(5 * NFUSE_);
  bf16* bp = (bf16*)(ws + o);
  size_t ob = 0;
  auto alloc_b = [&](size_t n) { bf16* p = bp + ob; ob += n; return p; };
  bf16* QKV  = alloc_b((size_t)N_ * QKV3_);
  bf16* hb   = alloc_b((size_t)N_ * H_);
  bf16* gated= alloc_b((size_t)N_ * H_);
  bf16* t1b  = alloc_b((size_t)N_ * DFF_);
  bf16* Wcat = alloc_b((size_t)5 * WCATSZ);
  bf16* W1t  = alloc_b((size_t)5 * W1TSZ);
  bf16* W2t  = alloc_b((size_t)5 * W2TSZ);
  unsigned int* pooled = (unsigned int*)(bp + ob);
  int* deg    = (int*)(pooled + G_ * H_);
  int* offs   = deg + N_;
  int* cursor = offs + N_ + 1;
  int* srcs   = cursor + N_;
  int* bsum   = srcs + E_;       // 64
  int* btop   = bsum + 64;       // 64

  // ---- weight prep ----
  int prep_total = 5 * PER_L + 5 * NFUSE_;
  k_prep<<<(prep_total + 255) / 256, 256, 0, stream>>>(Wq, Wk, Wv, Wskip, W1, W2,
                                                       bq, bk, bv, bskip, Wcat, W1t, W2t, bcat);

  // ---- CSR build (hierarchical scan) ----
  hipMemsetAsync(deg, 0, N_ * sizeof(int), stream);
  hipMemsetAsync(cursor, 0, N_ * sizeof(int), stream);
  k_count  <<<E_ / 256, 256, 0, stream>>>(edst, deg);
  k_bsum   <<<64, 256, 0, stream>>>(deg, bsum);
  k_btop   <<<1, 64, 0, stream>>>(bsum, btop);
  k_boffs  <<<64, 256, 0, stream>>>(deg, btop, offs);
  k_scatter<<<E_ / 256, 256, 0, stream>>>(esrc, edst, offs, cursor, srcs);

  // ---- embedding (+fused stats) + BN + GELU -> bf16 ----
  k_embed2<<<128, 256, 0, stream>>>(x, embW, embb, t1, stats, stats + 128 * 128);
  k_bn_finalize<128><<<1, 128, 0, stream>>>(stats, stats + 128 * 128, emb_g, emb_be, a_c, c_c);
  k_bn_apply_gelu_cast<128><<<N_ * H_ / 256, 256, 0, stream>>>(t1, a_c, c_c, hb);

  for (int l = 0; l < L_; ++l) {
    const float* Wb_ = Wbeta + (size_t)l * 3 * H_;
    const float* b1_ = b1 + (size_t)l * DFF_;
    const float* g1_ = g1 + (size_t)l * DFF_;
    const float* be1_= be1 + (size_t)l * DFF_;
    const float* b2_ = b2 + (size_t)l * H_;

    k_mfma<128, NFUSE_, 128, 2><<<dim3(N_ / 128, NFUSE_ / 128), 256, 0, stream>>>(
        hb, Wcat + (size_t)l * WCATSZ, bcat + (size_t)l * NFUSE_,
        nullptr, nullptr, QKV, xr, nullptr, nullptr);

    k_attn<<<N_ / 4, 256, 0, stream>>>(QKV, xr, Wb_, srcs, offs, gated);

    k_mfma<128, 512, 128, 3><<<dim3(N_ / 128, 4), 256, 0, stream>>>(
        gated, W1t + (size_t)l * W1TSZ, b1_, t1, nullptr, nullptr, nullptr,
        stats, stats + 128 * 512);

    k_bn_finalize<512><<<4, 128, 0, stream>>>(stats, stats + 128 * 512, g1_, be1_, a_c, c_c);
    k_bn_apply_gelu_cast<512><<<N_ * DFF_ / 256, 256, 0, stream>>>(t1, a_c, c_c, t1b);

    k_mfma<512, 128, 64, 1><<<dim3(N_ / 64, 1), 256, 0, stream>>>(
        t1b, W2t + (size_t)l * W2TSZ, b2_, h32, hb, nullptr, nullptr, nullptr, nullptr);
  }

  // ---- pooling + prediction ----
  k_pool_init<<<G_ * H_ / 64, 64, 0, stream>>>(pooled);
  k_pool<<<N_ * H_ / 256, 256, 0, stream>>>(h32, batch, pooled);
  k_pred<<<G_, 64, 0, stream>>>(pooled, predW, predb, (float*)d_out);
}